// Round 10
// baseline (23.664 us; speedup 1.0000x reference)
//
#include <hip/hip_runtime.h>
#include <math.h>

#define NB 8
#define NH 256
#define NW 256
#define NHW (NH*NW)
#define NTOT (NB*NHW)
#define NBLK (NB*NH)           // 2048 blocks, one row each
#define NSLOT 32               // data-atomic slots per component
#define NCTR 32                // level-1 finalize counters
#define PAD 64                 // ints/floats per slot = 256B = one L2 line
#define CLAMPI 1023

// ---------------------------------------------------------------------------
// Fused single kernel. 2048 blocks x 256 threads.
//  * Blocks 0..127 run the R9-proven vertical-EDT body for (b=blk>>4,
//    grp=blk&15): register scans, packed u16-pair output — published with
//    AGENT-scope stores, ordered before a per-image padded counter add by
//    __syncthreads' vmcnt drain + explicit vmcnt(0) (R6/R9-proven pattern,
//    no fences). fP/fN packed into one u32 each (clamped scans) to cut VGPRs.
//  * ALL blocks first load their logits/tgt row and compute the pk-independent
//    partials (sig, tv, inter, bce) — this hides under the producers' work.
//  * Thread 0 spins on imgCtr[image] (deadlock-free: producers are the 128
//    lowest block IDs, dispatched first; dependency only flows downward),
//    then the block reads its pk row uncached, runs the early-exit horizontal
//    EDT, and folds partials into 256B-padded atomic slots + counter tree
//    (R9-exact). Elected last block finalizes the scalar loss.
//  * imgCtr/posCnt/ctrT/acc zeroed by a 53KB hipMemsetAsync before launch.
// ---------------------------------------------------------------------------
__global__ __launch_bounds__(256) void k_fused(const float* __restrict__ logits,
                                               const float* __restrict__ tgt,
                                               unsigned int* __restrict__ pk,
                                               int* __restrict__ imgCtr,
                                               int* __restrict__ posCnt,
                                               int* __restrict__ ctrT,
                                               float* __restrict__ acc,
                                               float* __restrict__ out) {
    const int blk = blockIdx.x;
    const int j = threadIdx.x;
    const int base = blk * NW;          // consumer row
    const int b2 = blk >> 8;            // consumer image

    __shared__ float sp[NW];
    __shared__ float sn[NW + 8];
    __shared__ float red[5][4];
    __shared__ float red2[5];
    __shared__ int lastFlag;
    __shared__ int hpS;
    __shared__ int sTop[2][16][16];
    __shared__ int sBot[2][16][16];
    __shared__ int sc[4];

    // ---- consumer row loads issued immediately (independent of producers) ----
    const float x = logits[base + j];
    const float tv_f = tgt[base + j];

    // ================= producer role: vertical EDT (blocks 0..127) =========
    if (blk < 128) {
        const int b = blk >> 4;
        const int grp = blk & 15;
        const int jl = j & 15;
        const int c = j >> 4;            // chunk 0..15
        const int col = grp * 16 + jl;
        const int r0 = c * 16;
        const float* t = tgt + b * NHW + col;
        unsigned int* po = pk + b * NHW + col;

        unsigned int bits = 0;
#pragma unroll
        for (int r = 0; r < 16; ++r)
            bits |= ((t[(r0 + r) * NW] > 0.5f) ? 1u : 0u) << r;
        const unsigned int nbm = bits ^ 0xFFFFu;

        sTop[0][c][jl] = bits ? (r0 + __builtin_ctz(bits))      :  100000;
        sBot[0][c][jl] = bits ? (r0 + 31 - __builtin_clz(bits)) : -100000;
        sTop[1][c][jl] = nbm  ? (r0 + __builtin_ctz(nbm))       :  100000;
        sBot[1][c][jl] = nbm  ? (r0 + 31 - __builtin_clz(nbm))  : -100000;
        __syncthreads();

        {
            int v = __popc(bits);
            for (int o = 32; o > 0; o >>= 1) v += __shfl_down(v, o, 64);
            if ((j & 63) == 0) sc[j >> 6] = v;
        }

        int laP = -100000, laN = -100000;
        for (int cc = 0; cc < c; ++cc) {
            laP = max(laP, sBot[0][cc][jl]);
            laN = max(laN, sBot[1][cc][jl]);
        }
        int fbP = 100000, fbN = 100000;
        for (int cc = c + 1; cc < 16; ++cc) {
            fbP = min(fbP, sTop[0][cc][jl]);
            fbN = min(fbN, sTop[1][cc][jl]);
        }
        __syncthreads();
        if (j == 0) atomicAdd(&posCnt[b * PAD], sc[0] + sc[1] + sc[2] + sc[3]);

        // clamped fwd scan packed into u32 (values <= 1023 fit u16)
        unsigned int fPN[16];
        int cp = min((r0 - 1) - laP, CLAMPI);
        int cn = min((r0 - 1) - laN, CLAMPI);
#pragma unroll
        for (int r = 0; r < 16; ++r) {
            cp = ((bits >> r) & 1u) ? 0 : min(cp + 1, CLAMPI);
            cn = ((nbm  >> r) & 1u) ? 0 : min(cn + 1, CLAMPI);
            fPN[r] = (unsigned int)cp | ((unsigned int)cn << 16);
        }
        int bp = min(fbP - (r0 + 16), CLAMPI);
        int bn = min(fbN - (r0 + 16), CLAMPI);
#pragma unroll
        for (int r = 15; r >= 0; --r) {
            bp = ((bits >> r) & 1u) ? 0 : min(bp + 1, CLAMPI);
            bn = ((nbm  >> r) & 1u) ? 0 : min(bn + 1, CLAMPI);
            unsigned int gp = min((int)(fPN[r] & 0xFFFFu), bp);
            unsigned int gn = min((int)(fPN[r] >> 16), bn);
            __hip_atomic_store(&po[(r0 + r) * NW], gp | (gn << 16),
                               __ATOMIC_RELAXED, __HIP_MEMORY_SCOPE_AGENT);
        }
        // all waves' pk stores drained by __syncthreads' vmcnt(0); then signal
        __syncthreads();
        if (j == 0) {
            asm volatile("s_waitcnt vmcnt(0)" ::: "memory");
            atomicAdd(&imgCtr[b * PAD], 1);
        }
    }

    // ================= consumer role: pk-independent partials ==============
    const bool m = tv_f > 0.5f;
    const float tv = m ? 1.0f : 0.0f;
    const float sig = 1.0f / (1.0f + expf(-x));
    const float splus = (x > 0.0f) ? (x + log1pf(expf(-x))) : log1pf(expf(x));
    float v0 = sig;
    float v1 = tv;
    float v2 = m ? sig : 0.0f;
    float v3 = splus - x * tv;

    // ---- wait for this image's 16 producers (thread-0 spin, barrier release)
    if (j == 0) {
        while (__hip_atomic_load(&imgCtr[b2 * PAD], __ATOMIC_RELAXED,
                                 __HIP_MEMORY_SCOPE_AGENT) < 16)
            __builtin_amdgcn_s_sleep(2);
        hpS = __hip_atomic_load(&posCnt[b2 * PAD], __ATOMIC_RELAXED,
                                __HIP_MEMORY_SCOPE_AGENT);
    }
    __syncthreads();
    const int hp = hpS;

    // ---- horizontal EDT on the published column distances ----
    const unsigned int pv = __hip_atomic_load(&pk[base + j], __ATOMIC_RELAXED,
                                              __HIP_MEMORY_SCOPE_AGENT);
    const float dp = (float)(pv & 0xFFFFu);
    const float dn = (float)(pv >> 16);
    sp[j] = dp * dp;
    sn[j] = dn * dn;
    __syncthreads();

    const float* sel = m ? sn : sp;
    float best = sel[j];
#pragma unroll
    for (int d = 1; d <= 8; ++d) {
        const float dd = (float)(d * d);
        int kl = j - d; kl = kl < 0 ? 0 : kl;
        int kr = j + d; kr = kr > NW - 1 ? NW - 1 : kr;
        best = fminf(best, sel[kl] + dd);
        best = fminf(best, sel[kr] + dd);
    }
    for (int d = 9; d < NW; ++d) {
        const float dd = (float)d * (float)d;
        if (dd >= best) break;
        int kl = j - d; kl = kl < 0 ? 0 : kl;
        int kr = j + d; kr = kr > NW - 1 ? NW - 1 : kr;
        best = fminf(best, sel[kl] + dd);
        best = fminf(best, sel[kr] + dd);
    }

    float res = m ? (1.0f - sqrtf(best)) : sqrtf(best);
    if (hp == 0) res = 0.0f;
    float v4 = sig * res;

    // ---- block reduce + padded-slot atomics + counter tree (R9-exact) ----
    const int lane = j & 63, wid = j >> 6;
    for (int o = 32; o > 0; o >>= 1) {
        v0 += __shfl_down(v0, o, 64);
        v1 += __shfl_down(v1, o, 64);
        v2 += __shfl_down(v2, o, 64);
        v3 += __shfl_down(v3, o, 64);
        v4 += __shfl_down(v4, o, 64);
    }
    if (lane == 0) {
        red[0][wid] = v0; red[1][wid] = v1; red[2][wid] = v2;
        red[3][wid] = v3; red[4][wid] = v4;
    }
    __syncthreads();
    if (j < 5) {
        float p = red[j][0] + red[j][1] + red[j][2] + red[j][3];
        atomicAdd(&acc[(j * NSLOT + (blk & (NSLOT - 1))) * PAD], p);
    }
    if (j == 0) {
        asm volatile("s_waitcnt vmcnt(0)" ::: "memory");
        int flag = 0;
        int c1 = atomicAdd(&ctrT[(blk & (NCTR - 1)) * PAD], 1);
        if (c1 == NBLK / NCTR - 1) {
            int s = atomicAdd(&ctrT[NCTR * PAD], 1);
            flag = (s == NCTR - 1) ? 1 : 0;
        }
        lastFlag = flag;
    }
    __syncthreads();
    if (!lastFlag) return;

    // ---- elected last block: read padded slots + finalize ----
    if (j < 5 * NSLOT) {
        float v = __hip_atomic_load(&acc[j * PAD], __ATOMIC_RELAXED,
                                    __HIP_MEMORY_SCOPE_AGENT);
        for (int o = 16; o > 0; o >>= 1) v += __shfl_down(v, o, 32);
        if ((j & 31) == 0) red2[j >> 5] = v;
    }
    __syncthreads();
    if (j == 0) {
        float ssig  = red2[0];
        float st    = red2[1];
        float inter = red2[2];
        float sbce  = red2[3];
        float sbdy  = red2[4];
        const float SMOOTH = 1e-5f;
        float dice = 1.0f - (2.0f * inter + SMOOTH) / (ssig + st + SMOOTH);
        float n = (float)NTOT;
        out[0] = 0.5f * dice + 0.5f * (sbce / n) + 0.5f * (sbdy / n);
    }
}

extern "C" void kernel_launch(void* const* d_in, const int* in_sizes, int n_in,
                              void* d_out, int out_size, void* d_ws, size_t ws_size,
                              hipStream_t stream) {
    const float* logits = (const float*)d_in[0];
    const float* tgt    = (const float*)d_in[1];
    float* out = (float*)d_out;

    unsigned int* pk = (unsigned int*)d_ws;            // NTOT u32 (packed u16 pair)
    char* zbase = (char*)d_ws + (size_t)NTOT * 4;      // zeroed control region:
    int*   imgCtr = (int*)zbase;                       //  8 padded lines
    int*   posCnt = imgCtr + NB * PAD;                 //  8 padded lines
    int*   ctrT   = posCnt + NB * PAD;                 //  33 padded lines
    float* acc    = (float*)(ctrT + (NCTR + 1) * PAD); //  160 padded lines
    const size_t zbytes = (size_t)(NB + NB + NCTR + 1 + 5 * NSLOT) * PAD * 4;

    hipMemsetAsync(zbase, 0, zbytes, stream);
    k_fused<<<NBLK, 256, 0, stream>>>(logits, tgt, pk, imgCtr, posCnt, ctrT, acc, out);
}

// Round 11
// 18.013 us; speedup vs baseline: 1.3137x; 1.3137x over previous
//
#include <hip/hip_runtime.h>
#include <math.h>

#define NB 8
#define NH 256
#define NW 256
#define NHW (NH*NW)
#define NTOT (NB*NHW)
#define K2B (NB*NH)            // 2048 k2 blocks, one row each (R4/R9-proven)
#define NACC 4                 // accumulated components: sig, inter, bce, bdy
#define NSLOT 32               // data-atomic slots per component
#define NCTR 32                // level-1 completion counters
#define PAD 64                 // ints/floats per slot = 256B = one L2 line
#define CLAMPI 1023

// ---------------------------------------------------------------------------
// K1: vertical EDT, both masks, now 128 blocks x 1024 THREADS (16 waves =
// 4/SIMD on the 128 busy CUs, vs 1/SIMD in R9 -> latency hidden). Same
// 16-col groups (each row's 16 cols = one 64B line per load instr, perfect
// coalescing). Thread (jl=t&15, c=t>>4) owns rows [c*4, c*4+4).
// Carry-in via ctz/clz chunk-summary table (32KB LDS) + serial max/min
// loops (<=63 LDS reads, no barriers). Packed u16-pair u32 output.
// Block 0 zeroes the padded accumulator/counter lines (plain stores;
// dispatch-boundary coherence proven R4-R9).
// ---------------------------------------------------------------------------
__global__ __launch_bounds__(1024) void k1_edt_cols(const float* __restrict__ tgt,
                                                    unsigned int* __restrict__ pk,
                                                    int* __restrict__ cnts,
                                                    float* __restrict__ acc,
                                                    int* __restrict__ ctr) {
    const int tid = threadIdx.x;
    if (blockIdx.x == 0) {
        if (tid < NACC * NSLOT) acc[tid * PAD] = 0.0f;
        else if (tid >= 256 && tid < 256 + NCTR + 1) ctr[(tid - 256) * PAD] = 0;
    }

    const int blk = blockIdx.x;
    const int b = blk >> 4;
    const int grp = blk & 15;
    const int jl = tid & 15;
    const int c = tid >> 4;              // chunk 0..63
    const int col = grp * 16 + jl;
    const int r0 = c * 4;
    const float* t = tgt + b * NHW + col;
    unsigned int* po = pk + b * NHW + col;

    // ---- load 4 rows -> 4-bit mask ----
    unsigned int bits = 0;
#pragma unroll
    for (int r = 0; r < 4; ++r)
        bits |= ((t[(r0 + r) * NW] > 0.5f) ? 1u : 0u) << r;
    const unsigned int nbm = bits ^ 0xFu;

    // ---- chunk summaries (global row of first/last true, sentinels) ----
    __shared__ int sTop[2][64][16];
    __shared__ int sBot[2][64][16];
    __shared__ int sc[16];
    sTop[0][c][jl] = bits ? (r0 + __builtin_ctz(bits))      :  100000;
    sBot[0][c][jl] = bits ? (r0 + 31 - __builtin_clz(bits)) : -100000;
    sTop[1][c][jl] = nbm  ? (r0 + __builtin_ctz(nbm))       :  100000;
    sBot[1][c][jl] = nbm  ? (r0 + 31 - __builtin_clz(nbm))  : -100000;
    {
        int v = __popc(bits);
        for (int o = 32; o > 0; o >>= 1) v += __shfl_down(v, o, 64);
        if ((tid & 63) == 0) sc[tid >> 6] = v;
    }
    __syncthreads();

    // ---- cross-chunk carries (serial LDS loops, no barriers) ----
    int laP = -100000, laN = -100000;
    for (int cc = 0; cc < c; ++cc) {
        laP = max(laP, sBot[0][cc][jl]);
        laN = max(laN, sBot[1][cc][jl]);
    }
    int fbP = 100000, fbN = 100000;
    for (int cc = c + 1; cc < 64; ++cc) {
        fbP = min(fbP, sTop[0][cc][jl]);
        fbN = min(fbN, sTop[1][cc][jl]);
    }
    if (tid == 0) {
        int s = 0;
#pragma unroll
        for (int w = 0; w < 16; ++w) s += sc[w];
        cnts[blk] = s;                   // per-block pos count (plain store)
    }

    // ---- fwd scan (registers), bwd scan + combine + packed store ----
    int fP[4], fN[4];
    int cp = (r0 - 1) - laP;
    int cn = (r0 - 1) - laN;
#pragma unroll
    for (int r = 0; r < 4; ++r) {
        cp = ((bits >> r) & 1u) ? 0 : cp + 1;
        cn = ((nbm  >> r) & 1u) ? 0 : cn + 1;
        fP[r] = cp; fN[r] = cn;
    }
    int bp = fbP - (r0 + 4);
    int bn = fbN - (r0 + 4);
#pragma unroll
    for (int r = 3; r >= 0; --r) {
        bp = ((bits >> r) & 1u) ? 0 : bp + 1;
        bn = ((nbm  >> r) & 1u) ? 0 : bn + 1;
        int gp = min(min(fP[r], bp), CLAMPI);
        int gn = min(min(fN[r], bn), CLAMPI);
        po[(r0 + r) * NW] = (unsigned int)gp | ((unsigned int)gn << 16);
    }
}

// ---------------------------------------------------------------------------
// K2: R9-exact body (one row per block, 2048 blocks, early-exit outward
// search) with two trims: (1) sum(targets) dropped from the reduce — the
// elected block derives it from cnts[]; (2) one shared expf for sigmoid +
// softplus. Handoff: 256B-padded atomic slots + counter tree, vmcnt-ordered,
// fence-free (R9-proven).
// ---------------------------------------------------------------------------
__global__ __launch_bounds__(256) void k2_row_loss(const float* __restrict__ logits,
                                                   const unsigned int* __restrict__ pk,
                                                   const int* __restrict__ cnts,
                                                   int* __restrict__ ctr,
                                                   float* __restrict__ acc,
                                                   float* __restrict__ out) {
    const int bi = blockIdx.x;          // b*NH + row
    const int j = threadIdx.x;
    const int base = bi * NW;
    const int b = bi >> 8;

    __shared__ float sp[NW];
    __shared__ float sn[NW + 8];
    __shared__ float red[NACC][4];
    __shared__ float red2[NACC];
    __shared__ float redC[4];
    __shared__ int lastFlag;

    const unsigned int pv = pk[base + j];
    const float dp = (float)(pv & 0xFFFFu);
    const float dn = (float)(pv >> 16);
    sp[j] = dp * dp;
    sn[j] = dn * dn;
    const bool m = (pv & 0xFFFFu) == 0u;   // pos pixel iff vertical pos-dist 0
    const float x = logits[base + j];
    __syncthreads();

    const float* sel = m ? sn : sp;
    float best = sel[j];
#pragma unroll
    for (int d = 1; d <= 8; ++d) {
        const float dd = (float)(d * d);
        int kl = j - d; kl = kl < 0 ? 0 : kl;
        int kr = j + d; kr = kr > NW - 1 ? NW - 1 : kr;
        best = fminf(best, sel[kl] + dd);
        best = fminf(best, sel[kr] + dd);
    }
    for (int d = 9; d < NW; ++d) {
        const float dd = (float)d * (float)d;
        if (dd >= best) break;
        int kl = j - d; kl = kl < 0 ? 0 : kl;
        int kr = j + d; kr = kr > NW - 1 ? NW - 1 : kr;
        best = fminf(best, sel[kl] + dd);
        best = fminf(best, sel[kr] + dd);
    }

    float res = m ? (1.0f - sqrtf(best)) : sqrtf(best);

    // shared-exp sigmoid + softplus: e = exp(-|x|)
    const float e = expf(-fabsf(x));
    const float inv = 1.0f / (1.0f + e);
    const float sig = (x > 0.0f) ? inv : e * inv;
    const float splus = fmaxf(x, 0.0f) + log1pf(e);

    // has_pos gate for this image (uniform scalar loads, L2-hit)
    {
        int s = 0;
#pragma unroll
        for (int g = 0; g < 16; ++g) s += cnts[b * 16 + g];
        if (s == 0) res = 0.0f;
    }

    float v0 = sig;                          // sum(sig)
    float v1 = m ? sig : 0.0f;               // inter
    float v2 = splus - (m ? x : 0.0f);       // bce sum
    float v3 = sig * res;                    // boundary sum

    const int lane = j & 63, wid = j >> 6;
    for (int o = 32; o > 0; o >>= 1) {
        v0 += __shfl_down(v0, o, 64);
        v1 += __shfl_down(v1, o, 64);
        v2 += __shfl_down(v2, o, 64);
        v3 += __shfl_down(v3, o, 64);
    }
    if (lane == 0) {
        red[0][wid] = v0; red[1][wid] = v1; red[2][wid] = v2; red[3][wid] = v3;
    }
    __syncthreads();
    if (j < NACC) {
        float p = red[j][0] + red[j][1] + red[j][2] + red[j][3];
        atomicAdd(&acc[(j * NSLOT + (bi & (NSLOT - 1))) * PAD], p);
    }
    if (j == 0) {
        // order this wave's data atomics before the completion counts
        asm volatile("s_waitcnt vmcnt(0)" ::: "memory");
        int flag = 0;
        int c1 = atomicAdd(&ctr[(bi & (NCTR - 1)) * PAD], 1);
        if (c1 == K2B / NCTR - 1) {
            int s = atomicAdd(&ctr[NCTR * PAD], 1);
            flag = (s == NCTR - 1) ? 1 : 0;
        }
        lastFlag = flag;
    }
    __syncthreads();
    if (!lastFlag) return;

    // ---- elected last block: read padded slots + cnts, finalize ----
    if (j < NACC * NSLOT) {
        float v = __hip_atomic_load(&acc[j * PAD], __ATOMIC_RELAXED,
                                    __HIP_MEMORY_SCOPE_AGENT);
        for (int o = 16; o > 0; o >>= 1) v += __shfl_down(v, o, 32);
        if ((j & 31) == 0) red2[j >> 5] = v;
    }
    {
        float ct = (j < 128) ? (float)cnts[j] : 0.0f;
        for (int o = 32; o > 0; o >>= 1) ct += __shfl_down(ct, o, 64);
        if (lane == 0) redC[wid] = ct;
    }
    __syncthreads();
    if (j == 0) {
        float ssig  = red2[0];
        float inter = red2[1];
        float sbce  = red2[2];
        float sbdy  = red2[3];
        float st    = redC[0] + redC[1] + redC[2] + redC[3];  // sum(targets)
        const float SMOOTH = 1e-5f;
        float dice = 1.0f - (2.0f * inter + SMOOTH) / (ssig + st + SMOOTH);
        float n = (float)NTOT;
        out[0] = 0.5f * dice + 0.5f * (sbce / n) + 0.5f * (sbdy / n);
    }
}

extern "C" void kernel_launch(void* const* d_in, const int* in_sizes, int n_in,
                              void* d_out, int out_size, void* d_ws, size_t ws_size,
                              hipStream_t stream) {
    const float* logits = (const float*)d_in[0];
    const float* tgt    = (const float*)d_in[1];
    float* out = (float*)d_out;

    unsigned int* pk = (unsigned int*)d_ws;            // NTOT u32 (packed u16 pair)
    float* acc = (float*)d_ws + NTOT;                  // NACC*NSLOT x 256B padded
    int*   ctr = (int*)(acc + NACC * NSLOT * PAD);     // (NCTR+1) x 256B padded
    int*   cnts = ctr + (NCTR + 1) * PAD;              // 128 ints

    k1_edt_cols<<<NB * 16, 1024, 0, stream>>>(tgt, pk, cnts, acc, ctr);
    k2_row_loss<<<K2B, 256, 0, stream>>>(logits, pk, cnts, ctr, acc, out);
}